// Round 6
// baseline (709.072 us; speedup 1.0000x reference)
//
#include <hip/hip_runtime.h>
#include <stdint.h>

#define NB 64      // batch
#define NP 576     // patches
#define ND 768     // dim
#define NG 64      // groups
#define NN 65      // groups + 1 (cls)
#define NSTEPS 8
#define FLOORV 1.0e-4f
#define EPSV   1.0e-4f
#define DTV    0.1f
#define GAMMAV 0.1f
#define KEEPC  288  // max(1, round(576*0.5))

// ---------------------------------------------------------------- K1: group means
__global__ __launch_bounds__(256) void k_group_means(const float* __restrict__ tokens,
                                                     const float* __restrict__ cls,
                                                     float* __restrict__ nodes,
                                                     const int* __restrict__ ghp,
                                                     const int* __restrict__ gwp) {
    int bx = blockIdx.x;
    int b = bx / NN, n = bx - b * NN;
    int tid = threadIdx.x;
    float* orow = nodes + (size_t)bx * ND;
    if (n == 0) {
        for (int d = tid; d < ND; d += 256) orow[d] = cls[(size_t)b * ND + d];
        return;
    }
    int grid_h = *ghp, grid_w = *gwp;
    int gh = (grid_h + 7) / 8, gw = (grid_w + 7) / 8;
    int g = n - 1, gr = g >> 3, gc = g & 7;
    int r0 = gr * gh, r1 = (gr == 7) ? grid_h : min((gr + 1) * gh, grid_h);
    int c0 = gc * gw, c1 = (gc == 7) ? grid_w : min((gc + 1) * gw, grid_w);
    int cnt = (r1 > r0 && c1 > c0) ? (r1 - r0) * (c1 - c0) : 0;
    float cf = (float)max(cnt, 1);
    const float* tb = tokens + (size_t)b * NP * ND;
    for (int d = tid; d < ND; d += 256) {
        float acc = 0.f;
        for (int r = r0; r < r1; ++r)
            for (int c = c0; c < c1; ++c)
                acc += tb[(size_t)(r * grid_w + c) * ND + d];
        orow[d] = acc / cf;
    }
}

// ---------------------------------------------------------------- K2: proj = nodes @ W^T (NT gemm)
__global__ __launch_bounds__(256) void k_gemm_nt(const float* __restrict__ A,
                                                 const float* __restrict__ Bm,
                                                 float* __restrict__ Cm) {
    __shared__ float As[32][68];
    __shared__ float Bs[32][68];
    int tid = threadIdx.x;
    int m0 = blockIdx.x * 64, n0 = blockIdx.y * 64;
    int tx = tid & 15, ty = tid >> 4;
    float acc[4][4];
#pragma unroll
    for (int i = 0; i < 4; ++i)
#pragma unroll
        for (int j = 0; j < 4; ++j) acc[i][j] = 0.f;
    int lrow = tid >> 3, lq = tid & 7;
    for (int k0 = 0; k0 < ND; k0 += 32) {
#pragma unroll
        for (int l = 0; l < 2; ++l) {
            int row = lrow + l * 32;
            float4 va = *(const float4*)&A[(size_t)(m0 + row) * ND + k0 + lq * 4];
            As[lq * 4 + 0][row] = va.x; As[lq * 4 + 1][row] = va.y;
            As[lq * 4 + 2][row] = va.z; As[lq * 4 + 3][row] = va.w;
            float4 vb = *(const float4*)&Bm[(size_t)(n0 + row) * ND + k0 + lq * 4];
            Bs[lq * 4 + 0][row] = vb.x; Bs[lq * 4 + 1][row] = vb.y;
            Bs[lq * 4 + 2][row] = vb.z; Bs[lq * 4 + 3][row] = vb.w;
        }
        __syncthreads();
#pragma unroll
        for (int kk = 0; kk < 32; ++kk) {
            float4 a4 = *(const float4*)&As[kk][ty * 4];
            float4 b4 = *(const float4*)&Bs[kk][tx * 4];
            float av[4] = {a4.x, a4.y, a4.z, a4.w};
            float bv[4] = {b4.x, b4.y, b4.z, b4.w};
#pragma unroll
            for (int i = 0; i < 4; ++i)
#pragma unroll
                for (int j = 0; j < 4; ++j) acc[i][j] += av[i] * bv[j];
        }
        __syncthreads();
    }
#pragma unroll
    for (int i = 0; i < 4; ++i) {
        float4 o = make_float4(acc[i][0], acc[i][1], acc[i][2], acc[i][3]);
        *(float4*)&Cm[(size_t)(m0 + ty * 4 + i) * ND + n0 + tx * 4] = o;
    }
}

// ---------------------------------------------------------------- K3: row-normalize proj, sq = sum(projN^2)
__global__ __launch_bounds__(256) void k_normalize(float* __restrict__ proj, float* __restrict__ sqv) {
    int r = blockIdx.x, tid = threadIdx.x;
    __shared__ double red[8];
    __shared__ float invs;
    float* row = proj + (size_t)r * ND;
    double s = 0.0;
    for (int d = tid; d < ND; d += 256) { double v = (double)row[d]; s += v * v; }
#pragma unroll
    for (int off = 32; off; off >>= 1) s += __shfl_down(s, off, 64);
    int wid = tid >> 6, lane = tid & 63;
    if (lane == 0) red[wid] = s;
    __syncthreads();
    if (tid == 0) invs = (float)(1.0 / fmax(sqrt(red[0] + red[1] + red[2] + red[3]), 1e-12));
    __syncthreads();
    float inv = invs;
    double s2 = 0.0;
    for (int d = tid; d < ND; d += 256) {
        float v = row[d] * inv; row[d] = v; s2 += (double)v * (double)v;
    }
#pragma unroll
    for (int off = 32; off; off >>= 1) s2 += __shfl_down(s2, off, 64);
    __syncthreads();
    if (lane == 0) red[wid] = s2;
    __syncthreads();
    if (tid == 0) sqv[r] = (float)(red[0] + red[1] + red[2] + red[3]);
}

// ---------------------------------------------------------------- K4: C init = with_floor(exp(-d2)), write d_hist[:,0]
__global__ __launch_bounds__(256) void k_pairwise(const float* __restrict__ proj,
                                                  const float* __restrict__ sqv,
                                                  float* __restrict__ dhist) {
    int b = blockIdx.x, tid = threadIdx.x;
    int tx = tid & 15, ty = tid >> 4;
    __shared__ float Ps[NN][65];
    float acc[5][5];
#pragma unroll
    for (int a = 0; a < 5; ++a)
#pragma unroll
        for (int c = 0; c < 5; ++c) acc[a][c] = 0.f;
    const float* Pb = proj + (size_t)b * NN * ND;
    for (int k0 = 0; k0 < ND; k0 += 64) {
        __syncthreads();
        for (int idx = tid; idx < NN * 64; idx += 256) {
            int i = idx >> 6, kk = idx & 63;
            Ps[i][kk] = Pb[(size_t)i * ND + k0 + kk];
        }
        __syncthreads();
        for (int kk = 0; kk < 64; ++kk) {
            float av[5], bv[5];
#pragma unroll
            for (int a = 0; a < 5; ++a) { int i = ty + 16 * a; av[a] = (i < NN) ? Ps[i][kk] : 0.f; }
#pragma unroll
            for (int c = 0; c < 5; ++c) { int j = tx + 16 * c; bv[c] = (j < NN) ? Ps[j][kk] : 0.f; }
#pragma unroll
            for (int a = 0; a < 5; ++a)
#pragma unroll
                for (int c = 0; c < 5; ++c) acc[a][c] += av[a] * bv[c];
        }
    }
#pragma unroll
    for (int a = 0; a < 5; ++a)
#pragma unroll
        for (int c = 0; c < 5; ++c) {
            int i = ty + 16 * a, j = tx + 16 * c;
            if (i < NN && j < NN) {
                float d2 = fmaxf(sqv[b * NN + i] + sqv[b * NN + j] - 2.0f * acc[a][c], 0.f);
                double cv = exp(-(double)d2);   // TAU = 1
                float cf = (i == j) ? 0.f : fmaxf((float)cv, FLOORV);
                dhist[(size_t)b * 9 * NN * NN + (size_t)i * NN + j] = cf;
            }
        }
}

// ---------------------------------------------------------------- helper: readlane broadcast (literal lane)
__device__ __forceinline__ float rl(float v, int l) {
    return __int_as_float(__builtin_amdgcn_readlane(__float_as_int(v), l));
}

// ================================================================ K5 macro machinery
// Row of the 65x65 system held as 64 INDEPENDENT NAMED SCALARS a1..a64
// (columns 1..64) + ar (rhs). No array, no reference, no recursion ->
// nothing for SROA/mem2reg to fail on; values are SSA from birth.
// Rounds 1-5 post-mortem: every array formulation (pragma loops, constant
// bounds, template recursion, launch_bounds budget) left A_ in scratch
// (VGPR 52/72/68, ~88% stall on L1/L2-absorbed spill traffic).
#define REP64(M) \
  M(1) M(2) M(3) M(4) M(5) M(6) M(7) M(8) M(9) M(10) M(11) M(12) M(13) M(14) M(15) M(16) \
  M(17) M(18) M(19) M(20) M(21) M(22) M(23) M(24) M(25) M(26) M(27) M(28) M(29) M(30) M(31) M(32) \
  M(33) M(34) M(35) M(36) M(37) M(38) M(39) M(40) M(41) M(42) M(43) M(44) M(45) M(46) M(47) M(48) \
  M(49) M(50) M(51) M(52) M(53) M(54) M(55) M(56) M(57) M(58) M(59) M(60) M(61) M(62) M(63) M(64)

#define REP64_2(M, K) \
  M(1,K) M(2,K) M(3,K) M(4,K) M(5,K) M(6,K) M(7,K) M(8,K) M(9,K) M(10,K) M(11,K) M(12,K) \
  M(13,K) M(14,K) M(15,K) M(16,K) M(17,K) M(18,K) M(19,K) M(20,K) M(21,K) M(22,K) M(23,K) M(24,K) \
  M(25,K) M(26,K) M(27,K) M(28,K) M(29,K) M(30,K) M(31,K) M(32,K) M(33,K) M(34,K) M(35,K) M(36,K) \
  M(37,K) M(38,K) M(39,K) M(40,K) M(41,K) M(42,K) M(43,K) M(44,K) M(45,K) M(46,K) M(47,K) M(48,K) \
  M(49,K) M(50,K) M(51,K) M(52,K) M(53,K) M(54,K) M(55,K) M(56,K) M(57,K) M(58,K) M(59,K) M(60,K) \
  M(61,K) M(62,K) M(63,K) M(64,K)

// build: load, accumulate degree, negate + diagonal fix
#define LD(J)  float a##J = crow[J];
#define ACCJ(J) deg += a##J;
#define FIXJ(J) a##J = ((J) == i_own) ? diag : -a##J;
// round 0 (pivot = row 0, values broadcast from v0)
#define R0(J)  a##J = __builtin_fmaf(l0, rl(v0, (J) - 1), a##J);
// elimination round K: update column J of own row (J>K only; literal guard folds)
#define UPD(J, K) if ((J) > (K)) a##J = __builtin_fmaf(ln, rl(a##J, (K) - 1), a##J);
#define ROUND(K) { \
    float pk = rl(a##K, (K) - 1); \
    float invp = 1.0f / pk; \
    inv_own = (lane == (K) - 1) ? invp : inv_own; \
    float l = (lane >= (K)) ? a##K * invp : 0.f; \
    float ln = -l; \
    REP64_2(UPD, K) \
    ar = __builtin_fmaf(ln, rl(ar, (K) - 1), ar); \
  }
// back-substitution step I (descending)
#define BS(I) { \
    float t = (rhs_ - acc) * inv_own; \
    float pi = rl(t, (I) - 1); \
    p_own = (i_own == (I)) ? t : p_own; \
    acc = __builtin_fmaf((i_own < (I)) ? a##I : 0.f, pi, acc); \
  }

// ---------------------------------------------------------------- K5: 8-step physarum dynamics
// ONE WAVE per batch. Lane L owns row L+1 as named scalars (see above).
// Pivot-row broadcast = v_readlane (literal lane). Wave-synchronous LDS
// handoffs (pd, Cs) fenced with __threadfence_block().
// Arithmetic bit-identical to rounds 1-5 (all PASSED, absmax 0.0039).
__global__ __launch_bounds__(64, 1) void k_dynamics(float* __restrict__ dhist,
                                                    float* __restrict__ qhist,
                                                    double* __restrict__ part) {
    int b = blockIdx.x;
    int lane = threadIdx.x;               // 0..63, one full wave
    __shared__ float Cs[NN * NN];         // conductance fp32 (16.9 KB)
    __shared__ float pd[NN];              // potentials
    float* C0 = dhist + (size_t)b * 9 * NN * NN;
    for (int t = lane; t < NN * NN; t += 64) Cs[t] = C0[t];
    __threadfence_block();

    const int i_own = lane + 1;           // row owned by this lane (1..64)
    double stable = 0.0, sparse = 0.0;

#pragma unroll 1
    for (int step = 0; step < NSTEPS; ++step) {
        // ---- build row i_own as named scalars: a_J = -C[i][J], diag = deg+eps
        const float* crow = Cs + (size_t)i_own * NN;
        REP64(LD)                          // a1..a64 = crow[1..64]
        float c0v = crow[0];
        float deg = c0v;
        REP64(ACCJ)                        // deg = sum of full row (diag entry is 0)
        float diag = deg + EPSV;
        REP64(FIXJ)                        // negate off-diag, install diagonal
        float ar = -(1.0f / 64.0f);        // rhs for rows >= 1

        // ---- round 0: pivot = row 0 (A[0][j] = -C[0][j], rhs0 = 1)
        float v0 = Cs[lane + 1];           // C[0][lane+1], reused for p0 later
        float s0 = v0;
#pragma unroll
        for (int off = 1; off < 64; off <<= 1) s0 += __shfl_xor(s0, off, 64);
        float d0 = s0 + EPSV;              // A[0][0] (C[0][0] = 0)
        float invd0 = 1.0f / d0;
        float l0 = -c0v * invd0;           // A[i][0] / A[0][0]
        REP64(R0)                          // a_J -= l0 * (-C[0][J])
        ar -= l0;                          // rhs -= l0 * 1

        // ---- rounds 1..63 hand-expanded; round 64 captures last diagonal
        float inv_own = 0.f;
        ROUND(1)  ROUND(2)  ROUND(3)  ROUND(4)  ROUND(5)  ROUND(6)  ROUND(7)  ROUND(8)
        ROUND(9)  ROUND(10) ROUND(11) ROUND(12) ROUND(13) ROUND(14) ROUND(15) ROUND(16)
        ROUND(17) ROUND(18) ROUND(19) ROUND(20) ROUND(21) ROUND(22) ROUND(23) ROUND(24)
        ROUND(25) ROUND(26) ROUND(27) ROUND(28) ROUND(29) ROUND(30) ROUND(31) ROUND(32)
        ROUND(33) ROUND(34) ROUND(35) ROUND(36) ROUND(37) ROUND(38) ROUND(39) ROUND(40)
        ROUND(41) ROUND(42) ROUND(43) ROUND(44) ROUND(45) ROUND(46) ROUND(47) ROUND(48)
        ROUND(49) ROUND(50) ROUND(51) ROUND(52) ROUND(53) ROUND(54) ROUND(55) ROUND(56)
        ROUND(57) ROUND(58) ROUND(59) ROUND(60) ROUND(61) ROUND(62) ROUND(63)
        {   // round 64: capture only
            float pk = rl(a64, 63);
            float invp = 1.0f / pk;
            inv_own = (lane == 63) ? invp : inv_own;
        }

        // ---- back substitution (named scalars, readlane chain, I = 64..1)
        float rhs_ = ar;
        float acc = 0.f, p_own = 0.f;
        BS(64) BS(63) BS(62) BS(61) BS(60) BS(59) BS(58) BS(57)
        BS(56) BS(55) BS(54) BS(53) BS(52) BS(51) BS(50) BS(49)
        BS(48) BS(47) BS(46) BS(45) BS(44) BS(43) BS(42) BS(41)
        BS(40) BS(39) BS(38) BS(37) BS(36) BS(35) BS(34) BS(33)
        BS(32) BS(31) BS(30) BS(29) BS(28) BS(27) BS(26) BS(25)
        BS(24) BS(23) BS(22) BS(21) BS(20) BS(19) BS(18) BS(17)
        BS(16) BS(15) BS(14) BS(13) BS(12) BS(11) BS(10) BS(9)
        BS(8)  BS(7)  BS(6)  BS(5)  BS(4)  BS(3)  BS(2)  BS(1)
        pd[i_own] = p_own;
        // p0 = (1 + sum_j C[0][j]*p_j) / d0  (row 0 never modified)
        float sp = v0 * p_own;
#pragma unroll
        for (int off = 1; off < 64; off <<= 1) sp += __shfl_xor(sp, off, 64);
        if (lane == 0) pd[0] = (1.0f + sp) * invd0;
        __threadfence_block();

        // ---- flow + conductance update (fp32, matches reference)
        float* qout = qhist + ((size_t)b * NSTEPS + step) * NN * NN;
        float* dout = dhist + ((size_t)b * 9 + step + 1) * NN * NN;
        for (int t = lane; t < NN * NN; t += 64) {
            int i = t / NN, j = t - i * NN;
            float c = Cs[t];
            float fl = c * (pd[i] - pd[j]);
            qout[t] = fl;
            float rr = fabsf(fl); rr = rr / (1.0f + rr);
            float cn = c + DTV * (rr - GAMMAV * c);
            float cnf = (i == j) ? 0.0f : fmaxf(cn, FLOORV);
            Cs[t] = cnf;
            dout[t] = cnf;
            stable += fabs((double)cnf - (double)c);
            if (step == NSTEPS - 1 && i > 0 && j > 0) sparse += (double)cnf;
        }
        __threadfence_block();
    }

#pragma unroll
    for (int off = 32; off; off >>= 1) {
        stable += __shfl_down(stable, off, 64);
        sparse += __shfl_down(sparse, off, 64);
    }
    if (lane == 0) {
        part[b]      = sparse;
        part[NB + b] = stable;
    }
}

// ---------------------------------------------------------------- K6: scores, top-k masks, gid, group_scores
__global__ __launch_bounds__(256) void k_scores(const float* __restrict__ qhist,
                                                const float* __restrict__ local,
                                                const int* __restrict__ ghp,
                                                const int* __restrict__ gwp,
                                                float* __restrict__ keep,
                                                float* __restrict__ patch,
                                                float* __restrict__ gidout,
                                                float* __restrict__ gsout) {
    int b = blockIdx.x, tid = threadIdx.x;
    __shared__ double gf[NG];
    __shared__ double ts[NP];
    __shared__ double red[8];
    __shared__ double stats[2];
    if (tid < NG) {
        const float* qrow = qhist + ((size_t)b * NSTEPS + (NSTEPS - 1)) * NN * NN + (size_t)(tid + 1) * NN;
        double s = 0.0;
        for (int j = 0; j < NN; ++j) s += fabs((double)qrow[j]);
        gf[tid] = s;
    }
    __syncthreads();
    if (tid < 64) {
        double v = gf[tid];
        double s = v;
#pragma unroll
        for (int off = 32; off; off >>= 1) s += __shfl_down(s, off, 64);
        double mean = __shfl(s, 0, 64) / (double)NG;
        double d = v - mean, ss = d * d;
#pragma unroll
        for (int off = 32; off; off >>= 1) ss += __shfl_down(ss, off, 64);
        if (tid == 0) { stats[0] = mean; stats[1] = 1.0 / fmax(sqrt(ss / (NG - 1)), 1e-6); }
    }
    const float* lrow = local + (size_t)b * NP;
    double s1 = 0.0;
    for (int p = tid; p < NP; p += 256) s1 += (double)lrow[p];
#pragma unroll
    for (int off = 32; off; off >>= 1) s1 += __shfl_down(s1, off, 64);
    int wid = tid >> 6, lane = tid & 63;
    if (lane == 0) red[wid] = s1;
    __syncthreads();
    double lmean = (red[0] + red[1] + red[2] + red[3]) / (double)NP;
    double s2 = 0.0;
    for (int p = tid; p < NP; p += 256) { double d = (double)lrow[p] - lmean; s2 += d * d; }
#pragma unroll
    for (int off = 32; off; off >>= 1) s2 += __shfl_down(s2, off, 64);
    __syncthreads();
    if (lane == 0) red[wid] = s2;
    __syncthreads();
    double linv = 1.0 / fmax(sqrt((red[0] + red[1] + red[2] + red[3]) / (double)(NP - 1)), 1e-6);
    double gmean = stats[0], ginv = stats[1];
    int grid_h = *ghp, grid_w = *gwp;
    int gh = (grid_h + 7) / 8, gw = (grid_w + 7) / 8;
    for (int p = tid; p < NP; p += 256) {
        int row = p / grid_w, col = p - row * grid_w;
        int g = min(row / gh, 7) * 8 + min(col / gw, 7);
        double gsc = (gf[g] - gmean) * ginv;
        double lsc = ((double)lrow[p] - lmean) * linv;
        ts[p] = gsc + 0.5 * lsc;  // FLOW_W=1, LOCAL_W=0.5
        gidout[(size_t)b * NP + p] = (float)g;
        gsout[(size_t)b * NP + p]  = (float)gsc;
    }
    __syncthreads();
    for (int p = tid; p < NP; p += 256) {
        double sp = ts[p];
        int c = 0;
        for (int qq = 0; qq < NP; ++qq) {
            double v = ts[qq];
            c += (v > sp) || (v == sp && qq < p);
        }
        float kf = (c < KEEPC) ? 1.0f : 0.0f;
        patch[(size_t)b * NP + p] = kf;
        keep[(size_t)b * (NP + 1) + 1 + p] = kf;
    }
    if (tid == 0) keep[(size_t)b * (NP + 1)] = 1.0f;
}

// ---------------------------------------------------------------- K7: routing rows
__global__ void k_routing(const float* __restrict__ dhist, float* __restrict__ rout) {
    int b = blockIdx.x, tid = threadIdx.x;  // 64 threads
    const float* Crow = dhist + ((size_t)b * 9 + 8) * NN * NN + (size_t)(tid + 1) * NN + 1;
    double s = 0.0;
    for (int j = 0; j < NG; ++j) s += (double)Crow[j];
    double inv = 1.0 / fmax(s, 1e-6);
    float* orow = rout + ((size_t)b * NG + tid) * NG;
    for (int j = 0; j < NG; ++j) orow[j] = (float)((double)Crow[j] * inv);
}

// ---------------------------------------------------------------- K8: aux scalar reduction
__global__ void k_aux(const double* __restrict__ part, float* __restrict__ osp, float* __restrict__ ost) {
    int tid = threadIdx.x;  // 64 threads
    double sp = part[tid], st = part[NB + tid];
#pragma unroll
    for (int off = 32; off; off >>= 1) {
        sp += __shfl_down(sp, off, 64);
        st += __shfl_down(st, off, 64);
    }
    if (tid == 0) { *osp = (float)(sp / NB); *ost = (float)(st / NB); }
}

// ----------------------------------------------------------------
extern "C" void kernel_launch(void* const* d_in, const int* in_sizes, int n_in,
                              void* d_out, int out_size, void* d_ws, size_t ws_size,
                              hipStream_t stream) {
    const float* tokens = (const float*)d_in[0];
    const float* cls    = (const float*)d_in[1];
    const float* W      = (const float*)d_in[2];
    const float* local  = (const float*)d_in[3];
    const int* ghp = (const int*)d_in[4];
    const int* gwp = (const int*)d_in[5];

    float* out = (float*)d_out;
    float* o_keep  = out;                                   // NB x (NP+1)
    float* o_patch = o_keep + (size_t)NB * (NP + 1);        // NB x NP
    float* o_gid   = o_patch + (size_t)NB * NP;             // NB x NP
    float* o_gs    = o_gid + (size_t)NB * NP;               // NB x NP
    float* o_dh    = o_gs + (size_t)NB * NP;                // NB x 9 x NN x NN
    float* o_qh    = o_dh + (size_t)NB * 9 * NN * NN;       // NB x 8 x NN x NN
    float* o_rt    = o_qh + (size_t)NB * NSTEPS * NN * NN;  // NB x NG x NG
    float* o_sp    = o_rt + (size_t)NB * NG * NG;           // scalar
    float* o_st    = o_sp + 1;                              // scalar

    float* nodes = (float*)d_ws;                            // NB*NN x ND
    float* proj  = nodes + (size_t)NB * NN * ND;            // NB*NN x ND
    float* sqv   = proj + (size_t)NB * NN * ND;             // NB*NN
    double* part = (double*)(((uintptr_t)(sqv + NB * NN) + 15) & ~(uintptr_t)15);  // 2*NB

    k_group_means<<<NB * NN, 256, 0, stream>>>(tokens, cls, nodes, ghp, gwp);
    dim3 g2((NB * NN) / 64, ND / 64);
    k_gemm_nt<<<g2, 256, 0, stream>>>(nodes, W, proj);
    k_normalize<<<NB * NN, 256, 0, stream>>>(proj, sqv);
    k_pairwise<<<NB, 256, 0, stream>>>(proj, sqv, o_dh);
    k_dynamics<<<NB, 64, 0, stream>>>(o_dh, o_qh, part);
    k_scores<<<NB, 256, 0, stream>>>(o_qh, local, ghp, gwp, o_keep, o_patch, o_gid, o_gs);
    k_routing<<<NB, 64, 0, stream>>>(o_dh, o_rt);
    k_aux<<<1, 64, 0, stream>>>(part, o_sp, o_st);
}

// Round 8
// 707.730 us; speedup vs baseline: 1.0019x; 1.0019x over previous
//
#include <hip/hip_runtime.h>
#include <stdint.h>

#define NB 64      // batch
#define NP 576     // patches
#define ND 768     // dim
#define NG 64      // groups
#define NN 65      // groups + 1 (cls)
#define NSTEPS 8
#define FLOORV 1.0e-4f
#define EPSV   1.0e-4f
#define DTV    0.1f
#define GAMMAV 0.1f
#define KEEPC  288  // max(1, round(576*0.5))

// ---------------------------------------------------------------- K1: group means
__global__ __launch_bounds__(256) void k_group_means(const float* __restrict__ tokens,
                                                     const float* __restrict__ cls,
                                                     float* __restrict__ nodes,
                                                     const int* __restrict__ ghp,
                                                     const int* __restrict__ gwp) {
    int bx = blockIdx.x;
    int b = bx / NN, n = bx - b * NN;
    int tid = threadIdx.x;
    float* orow = nodes + (size_t)bx * ND;
    if (n == 0) {
        for (int d = tid; d < ND; d += 256) orow[d] = cls[(size_t)b * ND + d];
        return;
    }
    int grid_h = *ghp, grid_w = *gwp;
    int gh = (grid_h + 7) / 8, gw = (grid_w + 7) / 8;
    int g = n - 1, gr = g >> 3, gc = g & 7;
    int r0 = gr * gh, r1 = (gr == 7) ? grid_h : min((gr + 1) * gh, grid_h);
    int c0 = gc * gw, c1 = (gc == 7) ? grid_w : min((gc + 1) * gw, grid_w);
    int cnt = (r1 > r0 && c1 > c0) ? (r1 - r0) * (c1 - c0) : 0;
    float cf = (float)max(cnt, 1);
    const float* tb = tokens + (size_t)b * NP * ND;
    for (int d = tid; d < ND; d += 256) {
        float acc = 0.f;
        for (int r = r0; r < r1; ++r)
            for (int c = c0; c < c1; ++c)
                acc += tb[(size_t)(r * grid_w + c) * ND + d];
        orow[d] = acc / cf;
    }
}

// ---------------------------------------------------------------- K2: proj = nodes @ W^T (NT gemm)
__global__ __launch_bounds__(256) void k_gemm_nt(const float* __restrict__ A,
                                                 const float* __restrict__ Bm,
                                                 float* __restrict__ Cm) {
    __shared__ float As[32][68];
    __shared__ float Bs[32][68];
    int tid = threadIdx.x;
    int m0 = blockIdx.x * 64, n0 = blockIdx.y * 64;
    int tx = tid & 15, ty = tid >> 4;
    float acc[4][4];
#pragma unroll
    for (int i = 0; i < 4; ++i)
#pragma unroll
        for (int j = 0; j < 4; ++j) acc[i][j] = 0.f;
    int lrow = tid >> 3, lq = tid & 7;
    for (int k0 = 0; k0 < ND; k0 += 32) {
#pragma unroll
        for (int l = 0; l < 2; ++l) {
            int row = lrow + l * 32;
            float4 va = *(const float4*)&A[(size_t)(m0 + row) * ND + k0 + lq * 4];
            As[lq * 4 + 0][row] = va.x; As[lq * 4 + 1][row] = va.y;
            As[lq * 4 + 2][row] = va.z; As[lq * 4 + 3][row] = va.w;
            float4 vb = *(const float4*)&Bm[(size_t)(n0 + row) * ND + k0 + lq * 4];
            Bs[lq * 4 + 0][row] = vb.x; Bs[lq * 4 + 1][row] = vb.y;
            Bs[lq * 4 + 2][row] = vb.z; Bs[lq * 4 + 3][row] = vb.w;
        }
        __syncthreads();
#pragma unroll
        for (int kk = 0; kk < 32; ++kk) {
            float4 a4 = *(const float4*)&As[kk][ty * 4];
            float4 b4 = *(const float4*)&Bs[kk][tx * 4];
            float av[4] = {a4.x, a4.y, a4.z, a4.w};
            float bv[4] = {b4.x, b4.y, b4.z, b4.w};
#pragma unroll
            for (int i = 0; i < 4; ++i)
#pragma unroll
                for (int j = 0; j < 4; ++j) acc[i][j] += av[i] * bv[j];
        }
        __syncthreads();
    }
#pragma unroll
    for (int i = 0; i < 4; ++i) {
        float4 o = make_float4(acc[i][0], acc[i][1], acc[i][2], acc[i][3]);
        *(float4*)&Cm[(size_t)(m0 + ty * 4 + i) * ND + n0 + tx * 4] = o;
    }
}

// ---------------------------------------------------------------- K3: row-normalize proj, sq = sum(projN^2)
__global__ __launch_bounds__(256) void k_normalize(float* __restrict__ proj, float* __restrict__ sqv) {
    int r = blockIdx.x, tid = threadIdx.x;
    __shared__ double red[8];
    __shared__ float invs;
    float* row = proj + (size_t)r * ND;
    double s = 0.0;
    for (int d = tid; d < ND; d += 256) { double v = (double)row[d]; s += v * v; }
#pragma unroll
    for (int off = 32; off; off >>= 1) s += __shfl_down(s, off, 64);
    int wid = tid >> 6, lane = tid & 63;
    if (lane == 0) red[wid] = s;
    __syncthreads();
    if (tid == 0) invs = (float)(1.0 / fmax(sqrt(red[0] + red[1] + red[2] + red[3]), 1e-12));
    __syncthreads();
    float inv = invs;
    double s2 = 0.0;
    for (int d = tid; d < ND; d += 256) {
        float v = row[d] * inv; row[d] = v; s2 += (double)v * (double)v;
    }
#pragma unroll
    for (int off = 32; off; off >>= 1) s2 += __shfl_down(s2, off, 64);
    __syncthreads();
    if (lane == 0) red[wid] = s2;
    __syncthreads();
    if (tid == 0) sqv[r] = (float)(red[0] + red[1] + red[2] + red[3]);
}

// ---------------------------------------------------------------- K4: C init = with_floor(exp(-d2)), write d_hist[:,0]
__global__ __launch_bounds__(256) void k_pairwise(const float* __restrict__ proj,
                                                  const float* __restrict__ sqv,
                                                  float* __restrict__ dhist) {
    int b = blockIdx.x, tid = threadIdx.x;
    int tx = tid & 15, ty = tid >> 4;
    __shared__ float Ps[NN][65];
    float acc[5][5];
#pragma unroll
    for (int a = 0; a < 5; ++a)
#pragma unroll
        for (int c = 0; c < 5; ++c) acc[a][c] = 0.f;
    const float* Pb = proj + (size_t)b * NN * ND;
    for (int k0 = 0; k0 < ND; k0 += 64) {
        __syncthreads();
        for (int idx = tid; idx < NN * 64; idx += 256) {
            int i = idx >> 6, kk = idx & 63;
            Ps[i][kk] = Pb[(size_t)i * ND + k0 + kk];
        }
        __syncthreads();
        for (int kk = 0; kk < 64; ++kk) {
            float av[5], bv[5];
#pragma unroll
            for (int a = 0; a < 5; ++a) { int i = ty + 16 * a; av[a] = (i < NN) ? Ps[i][kk] : 0.f; }
#pragma unroll
            for (int c = 0; c < 5; ++c) { int j = tx + 16 * c; bv[c] = (j < NN) ? Ps[j][kk] : 0.f; }
#pragma unroll
            for (int a = 0; a < 5; ++a)
#pragma unroll
                for (int c = 0; c < 5; ++c) acc[a][c] += av[a] * bv[c];
        }
    }
#pragma unroll
    for (int a = 0; a < 5; ++a)
#pragma unroll
        for (int c = 0; c < 5; ++c) {
            int i = ty + 16 * a, j = tx + 16 * c;
            if (i < NN && j < NN) {
                float d2 = fmaxf(sqv[b * NN + i] + sqv[b * NN + j] - 2.0f * acc[a][c], 0.f);
                double cv = exp(-(double)d2);   // TAU = 1
                float cf = (i == j) ? 0.f : fmaxf((float)cv, FLOORV);
                dhist[(size_t)b * 9 * NN * NN + (size_t)i * NN + j] = cf;
            }
        }
}

// ---------------------------------------------------------------- helper: readlane broadcast (literal lane)
__device__ __forceinline__ float rl(float v, int l) {
    return __int_as_float(__builtin_amdgcn_readlane(__float_as_int(v), l));
}

// ================================================================ K5 macro machinery
// BLOCKED register solve, designed UNDER the empirically-observed ~68-VGPR
// allocation cap (rounds 1-6: every full-row-in-registers variant allocated
// 52-72 VGPRs and spilled; r3==r6 perf proves SROA promoted and the ALLOCATOR
// spilled). Hold only 32 columns in registers at a time:
//   Phase A: rounds 0..32 on left cols 1..32 (regs a1..a32); multipliers l
//            stored to lds_L (left cols evolve independently of right cols ->
//            bit-identical to flat elimination order).
//   Dump a* -> lds_U (back-sub needs rows<=32's U), reload right cols 33..64
//            into b1..b32 (same physical regs, disjoint live ranges).
//   Phase B: replay rounds 0..32 on right cols (l from lds_L, pivot row via
//            readlane) -- per-element fma sequence identical to flat order.
//   Phase C: rounds 33..63 on right cols; then the r6 back-sub chain with
//            coefs from b* (I>=33) / lds_U (I<=32).
// Max live ~52 regs < 68 -> no spill by construction. One wave, no barriers.
// (Round 7 never ran: container-acquisition infra failure. Resubmitted as-is
//  after a line-by-line re-audit found no defects.)
#define REP32(M) \
  M(1) M(2) M(3) M(4) M(5) M(6) M(7) M(8) M(9) M(10) M(11) M(12) M(13) M(14) M(15) M(16) \
  M(17) M(18) M(19) M(20) M(21) M(22) M(23) M(24) M(25) M(26) M(27) M(28) M(29) M(30) M(31) M(32)

#define REP32_2(M, K) \
  M(1,K) M(2,K) M(3,K) M(4,K) M(5,K) M(6,K) M(7,K) M(8,K) M(9,K) M(10,K) M(11,K) M(12,K) \
  M(13,K) M(14,K) M(15,K) M(16,K) M(17,K) M(18,K) M(19,K) M(20,K) M(21,K) M(22,K) M(23,K) M(24,K) \
  M(25,K) M(26,K) M(27,K) M(28,K) M(29,K) M(30,K) M(31,K) M(32,K)

// build left: load, accumulate degree (order j=1..32), negate + diagonal fix
#define LDA(J)   float a##J = crow[J];
#define ACCA(J)  deg += a##J;
#define ACCR(J)  deg += crow[32 + (J)];
#define FIXA(J)  a##J = ((J) == i_own) ? diag : -a##J;
// round 0 on left cols (pivot row 0 read directly from Cs row 0 - broadcast)
#define R0A(J)   a##J = __builtin_fmaf(l0, Cs[(J)], a##J);
// phase A elimination round K (1..32): update left cols J>K
#define UPDA(J, K) if ((J) > (K)) a##J = __builtin_fmaf(ln, rl(a##J, (K) - 1), a##J);
#define ROUNDA(K) { \
    float pk = rl(a##K, (K) - 1); \
    float invp = 1.0f / pk; \
    inv_own = (lane == (K) - 1) ? invp : inv_own; \
    float l = (lane >= (K)) ? a##K * invp : 0.f; \
    lds_L[(K) * 64 + lane] = l; \
    float ln = -l; \
    REP32_2(UPDA, K) \
    ar = __builtin_fmaf(ln, rl(ar, (K) - 1), ar); \
  }
// dump left U, build right cols
#define DUMPA(J) lds_U[lane * 33 + (J)] = a##J;
#define LDB(J)   float b##J = ((32 + (J)) == i_own) ? diag : -crow[32 + (J)];
// phase B: replay round 0 then rounds 1..32 on right cols (all cols, no guard)
#define R0B(J)   b##J = __builtin_fmaf(l0, Cs[32 + (J)], b##J);
#define UPDB(J, K) b##J = __builtin_fmaf(ln, rl(b##J, (K) - 1), b##J);
#define ROUNDB(K) { \
    float l = lds_L[(K) * 64 + lane]; \
    float ln = -l; \
    REP32_2(UPDB, K) \
  }
// phase C round (Q = K-32, both literal): update right cols J with 32+J > K
#define UPDC(J, K) if (((J) + 32) > (K)) b##J = __builtin_fmaf(ln, rl(b##J, (K) - 1), b##J);
#define ROUNDC(Q, K) { \
    float pk = rl(b##Q, (K) - 1); \
    float invp = 1.0f / pk; \
    inv_own = (lane == (K) - 1) ? invp : inv_own; \
    float l = (lane >= (K)) ? b##Q * invp : 0.f; \
    float ln = -l; \
    REP32_2(UPDC, K) \
    ar = __builtin_fmaf(ln, rl(ar, (K) - 1), ar); \
  }
// back-substitution: high steps (I>=33, coef in regs), low steps (I<=32, coef in lds_U)
#define BSH(Q, I) { \
    float t = (rhs_ - acc) * inv_own; \
    float pi = rl(t, (I) - 1); \
    p_own = (i_own == (I)) ? t : p_own; \
    acc = __builtin_fmaf((i_own < (I)) ? b##Q : 0.f, pi, acc); \
  }
#define BSL(I) { \
    float t = (rhs_ - acc) * inv_own; \
    float pi = rl(t, (I) - 1); \
    p_own = (i_own == (I)) ? t : p_own; \
    float u = lds_U[lane * 33 + (I)]; \
    acc = __builtin_fmaf((i_own < (I)) ? u : 0.f, pi, acc); \
  }

// ---------------------------------------------------------------- K5: 8-step physarum dynamics
__global__ __launch_bounds__(64, 1) void k_dynamics(float* __restrict__ dhist,
                                                    float* __restrict__ qhist,
                                                    double* __restrict__ part) {
    int b = blockIdx.x;
    int lane = threadIdx.x;               // 0..63, one full wave
    __shared__ float Cs[NN * NN];         // conductance fp32 (16.9 KB)
    __shared__ float pd[NN];              // potentials
    __shared__ float lds_L[33 * 64];      // phase-A multipliers (8.4 KB)
    __shared__ float lds_U[64 * 33];      // dumped left-U rows (8.4 KB)
    float* C0 = dhist + (size_t)b * 9 * NN * NN;
    for (int t = lane; t < NN * NN; t += 64) Cs[t] = C0[t];
    __threadfence_block();

    const int i_own = lane + 1;           // row owned by this lane (1..64)
    double stable = 0.0, sparse = 0.0;

#pragma unroll 1
    for (int step = 0; step < NSTEPS; ++step) {
        const float* crow = Cs + (size_t)i_own * NN;
        // ---- build: deg summed in flat order j=0..64 (bit-identical to r1-r6)
        float c0v = crow[0];
        float deg = c0v;
        REP32(LDA)                         // a1..a32 = crow[1..32]
        REP32(ACCA)                        // deg += a1..a32 (order 1..32)
        REP32(ACCR)                        // deg += crow[33..64] (order 33..64)
        float diag = deg + EPSV;
        REP32(FIXA)                        // negate off-diag, install diagonal (left)
        float ar = -(1.0f / 64.0f);        // rhs for rows >= 1

        // ---- round 0 on left cols (pivot = system row 0)
        float v0 = Cs[lane + 1];           // C[0][lane+1]
        float s0 = v0;
#pragma unroll
        for (int off = 1; off < 64; off <<= 1) s0 += __shfl_xor(s0, off, 64);
        float d0 = s0 + EPSV;              // A[0][0]
        float invd0 = 1.0f / d0;
        float l0 = -c0v * invd0;           // A[i][0] / A[0][0]
        REP32(R0A)                         // a_J += l0 * C[0][J]
        ar -= l0;                          // rhs -= l0 * 1

        // ---- phase A: rounds 1..32 on left cols, l recorded to lds_L
        float inv_own = 0.f;
        ROUNDA(1)  ROUNDA(2)  ROUNDA(3)  ROUNDA(4)  ROUNDA(5)  ROUNDA(6)  ROUNDA(7)  ROUNDA(8)
        ROUNDA(9)  ROUNDA(10) ROUNDA(11) ROUNDA(12) ROUNDA(13) ROUNDA(14) ROUNDA(15) ROUNDA(16)
        ROUNDA(17) ROUNDA(18) ROUNDA(19) ROUNDA(20) ROUNDA(21) ROUNDA(22) ROUNDA(23) ROUNDA(24)
        ROUNDA(25) ROUNDA(26) ROUNDA(27) ROUNDA(28) ROUNDA(29) ROUNDA(30) ROUNDA(31) ROUNDA(32)

        // ---- dump left U, load right cols (a* die here; b* reuse the regs)
        REP32(DUMPA)
        REP32(LDB)                         // b1..b32 = original right cols (+diag)

        // ---- phase B: replay rounds 0..32 on right cols (bit-identical order)
        REP32(R0B)                         // round 0: pivot row 0 right half from Cs
        ROUNDB(1)  ROUNDB(2)  ROUNDB(3)  ROUNDB(4)  ROUNDB(5)  ROUNDB(6)  ROUNDB(7)  ROUNDB(8)
        ROUNDB(9)  ROUNDB(10) ROUNDB(11) ROUNDB(12) ROUNDB(13) ROUNDB(14) ROUNDB(15) ROUNDB(16)
        ROUNDB(17) ROUNDB(18) ROUNDB(19) ROUNDB(20) ROUNDB(21) ROUNDB(22) ROUNDB(23) ROUNDB(24)
        ROUNDB(25) ROUNDB(26) ROUNDB(27) ROUNDB(28) ROUNDB(29) ROUNDB(30) ROUNDB(31) ROUNDB(32)

        // ---- phase C: rounds 33..63 on right cols
        ROUNDC(1,33)  ROUNDC(2,34)  ROUNDC(3,35)  ROUNDC(4,36)  ROUNDC(5,37)  ROUNDC(6,38)
        ROUNDC(7,39)  ROUNDC(8,40)  ROUNDC(9,41)  ROUNDC(10,42) ROUNDC(11,43) ROUNDC(12,44)
        ROUNDC(13,45) ROUNDC(14,46) ROUNDC(15,47) ROUNDC(16,48) ROUNDC(17,49) ROUNDC(18,50)
        ROUNDC(19,51) ROUNDC(20,52) ROUNDC(21,53) ROUNDC(22,54) ROUNDC(23,55) ROUNDC(24,56)
        ROUNDC(25,57) ROUNDC(26,58) ROUNDC(27,59) ROUNDC(28,60) ROUNDC(29,61) ROUNDC(30,62)
        ROUNDC(31,63)
        {   // round 64: capture last diagonal reciprocal
            float pk = rl(b32, 63);
            float invp = 1.0f / pk;
            inv_own = (lane == 63) ? invp : inv_own;
        }

        // ---- back substitution (descending I=64..1, same chain as r6)
        float rhs_ = ar;
        float acc = 0.f, p_own = 0.f;
        BSH(32,64) BSH(31,63) BSH(30,62) BSH(29,61) BSH(28,60) BSH(27,59) BSH(26,58) BSH(25,57)
        BSH(24,56) BSH(23,55) BSH(22,54) BSH(21,53) BSH(20,52) BSH(19,51) BSH(18,50) BSH(17,49)
        BSH(16,48) BSH(15,47) BSH(14,46) BSH(13,45) BSH(12,44) BSH(11,43) BSH(10,42) BSH(9,41)
        BSH(8,40)  BSH(7,39)  BSH(6,38)  BSH(5,37)  BSH(4,36)  BSH(3,35)  BSH(2,34)  BSH(1,33)
        BSL(32) BSL(31) BSL(30) BSL(29) BSL(28) BSL(27) BSL(26) BSL(25)
        BSL(24) BSL(23) BSL(22) BSL(21) BSL(20) BSL(19) BSL(18) BSL(17)
        BSL(16) BSL(15) BSL(14) BSL(13) BSL(12) BSL(11) BSL(10) BSL(9)
        BSL(8)  BSL(7)  BSL(6)  BSL(5)  BSL(4)  BSL(3)  BSL(2)  BSL(1)
        pd[i_own] = p_own;
        // p0 = (1 + sum_j C[0][j]*p_j) / d0  (row 0 never modified)
        float sp = v0 * p_own;
#pragma unroll
        for (int off = 1; off < 64; off <<= 1) sp += __shfl_xor(sp, off, 64);
        if (lane == 0) pd[0] = (1.0f + sp) * invd0;
        __threadfence_block();

        // ---- flow + conductance update (fp32, matches reference)
        float* qout = qhist + ((size_t)b * NSTEPS + step) * NN * NN;
        float* dout = dhist + ((size_t)b * 9 + step + 1) * NN * NN;
        for (int t = lane; t < NN * NN; t += 64) {
            int i = t / NN, j = t - i * NN;
            float c = Cs[t];
            float fl = c * (pd[i] - pd[j]);
            qout[t] = fl;
            float rr = fabsf(fl); rr = rr / (1.0f + rr);
            float cn = c + DTV * (rr - GAMMAV * c);
            float cnf = (i == j) ? 0.0f : fmaxf(cn, FLOORV);
            Cs[t] = cnf;
            dout[t] = cnf;
            stable += fabs((double)cnf - (double)c);
            if (step == NSTEPS - 1 && i > 0 && j > 0) sparse += (double)cnf;
        }
        __threadfence_block();
    }

#pragma unroll
    for (int off = 32; off; off >>= 1) {
        stable += __shfl_down(stable, off, 64);
        sparse += __shfl_down(sparse, off, 64);
    }
    if (lane == 0) {
        part[b]      = sparse;
        part[NB + b] = stable;
    }
}

// ---------------------------------------------------------------- K6: scores, top-k masks, gid, group_scores
__global__ __launch_bounds__(256) void k_scores(const float* __restrict__ qhist,
                                                const float* __restrict__ local,
                                                const int* __restrict__ ghp,
                                                const int* __restrict__ gwp,
                                                float* __restrict__ keep,
                                                float* __restrict__ patch,
                                                float* __restrict__ gidout,
                                                float* __restrict__ gsout) {
    int b = blockIdx.x, tid = threadIdx.x;
    __shared__ double gf[NG];
    __shared__ double ts[NP];
    __shared__ double red[8];
    __shared__ double stats[2];
    if (tid < NG) {
        const float* qrow = qhist + ((size_t)b * NSTEPS + (NSTEPS - 1)) * NN * NN + (size_t)(tid + 1) * NN;
        double s = 0.0;
        for (int j = 0; j < NN; ++j) s += fabs((double)qrow[j]);
        gf[tid] = s;
    }
    __syncthreads();
    if (tid < 64) {
        double v = gf[tid];
        double s = v;
#pragma unroll
        for (int off = 32; off; off >>= 1) s += __shfl_down(s, off, 64);
        double mean = __shfl(s, 0, 64) / (double)NG;
        double d = v - mean, ss = d * d;
#pragma unroll
        for (int off = 32; off; off >>= 1) ss += __shfl_down(ss, off, 64);
        if (tid == 0) { stats[0] = mean; stats[1] = 1.0 / fmax(sqrt(ss / (NG - 1)), 1e-6); }
    }
    const float* lrow = local + (size_t)b * NP;
    double s1 = 0.0;
    for (int p = tid; p < NP; p += 256) s1 += (double)lrow[p];
#pragma unroll
    for (int off = 32; off; off >>= 1) s1 += __shfl_down(s1, off, 64);
    int wid = tid >> 6, lane = tid & 63;
    if (lane == 0) red[wid] = s1;
    __syncthreads();
    double lmean = (red[0] + red[1] + red[2] + red[3]) / (double)NP;
    double s2 = 0.0;
    for (int p = tid; p < NP; p += 256) { double d = (double)lrow[p] - lmean; s2 += d * d; }
#pragma unroll
    for (int off = 32; off; off >>= 1) s2 += __shfl_down(s2, off, 64);
    __syncthreads();
    if (lane == 0) red[wid] = s2;
    __syncthreads();
    double linv = 1.0 / fmax(sqrt((red[0] + red[1] + red[2] + red[3]) / (double)(NP - 1)), 1e-6);
    double gmean = stats[0], ginv = stats[1];
    int grid_h = *ghp, grid_w = *gwp;
    int gh = (grid_h + 7) / 8, gw = (grid_w + 7) / 8;
    for (int p = tid; p < NP; p += 256) {
        int row = p / grid_w, col = p - row * grid_w;
        int g = min(row / gh, 7) * 8 + min(col / gw, 7);
        double gsc = (gf[g] - gmean) * ginv;
        double lsc = ((double)lrow[p] - lmean) * linv;
        ts[p] = gsc + 0.5 * lsc;  // FLOW_W=1, LOCAL_W=0.5
        gidout[(size_t)b * NP + p] = (float)g;
        gsout[(size_t)b * NP + p]  = (float)gsc;
    }
    __syncthreads();
    for (int p = tid; p < NP; p += 256) {
        double sp = ts[p];
        int c = 0;
        for (int qq = 0; qq < NP; ++qq) {
            double v = ts[qq];
            c += (v > sp) || (v == sp && qq < p);
        }
        float kf = (c < KEEPC) ? 1.0f : 0.0f;
        patch[(size_t)b * NP + p] = kf;
        keep[(size_t)b * (NP + 1) + 1 + p] = kf;
    }
    if (tid == 0) keep[(size_t)b * (NP + 1)] = 1.0f;
}

// ---------------------------------------------------------------- K7: routing rows
__global__ void k_routing(const float* __restrict__ dhist, float* __restrict__ rout) {
    int b = blockIdx.x, tid = threadIdx.x;  // 64 threads
    const float* Crow = dhist + ((size_t)b * 9 + 8) * NN * NN + (size_t)(tid + 1) * NN + 1;
    double s = 0.0;
    for (int j = 0; j < NG; ++j) s += (double)Crow[j];
    double inv = 1.0 / fmax(s, 1e-6);
    float* orow = rout + ((size_t)b * NG + tid) * NG;
    for (int j = 0; j < NG; ++j) orow[j] = (float)((double)Crow[j] * inv);
}

// ---------------------------------------------------------------- K8: aux scalar reduction
__global__ void k_aux(const double* __restrict__ part, float* __restrict__ osp, float* __restrict__ ost) {
    int tid = threadIdx.x;  // 64 threads
    double sp = part[tid], st = part[NB + tid];
#pragma unroll
    for (int off = 32; off; off >>= 1) {
        sp += __shfl_down(sp, off, 64);
        st += __shfl_down(st, off, 64);
    }
    if (tid == 0) { *osp = (float)(sp / NB); *ost = (float)(st / NB); }
}

// ----------------------------------------------------------------
extern "C" void kernel_launch(void* const* d_in, const int* in_sizes, int n_in,
                              void* d_out, int out_size, void* d_ws, size_t ws_size,
                              hipStream_t stream) {
    const float* tokens = (const float*)d_in[0];
    const float* cls    = (const float*)d_in[1];
    const float* W      = (const float*)d_in[2];
    const float* local  = (const float*)d_in[3];
    const int* ghp = (const int*)d_in[4];
    const int* gwp = (const int*)d_in[5];

    float* out = (float*)d_out;
    float* o_keep  = out;                                   // NB x (NP+1)
    float* o_patch = o_keep + (size_t)NB * (NP + 1);        // NB x NP
    float* o_gid   = o_patch + (size_t)NB * NP;             // NB x NP
    float* o_gs    = o_gid + (size_t)NB * NP;               // NB x NP
    float* o_dh    = o_gs + (size_t)NB * NP;                // NB x 9 x NN x NN
    float* o_qh    = o_dh + (size_t)NB * 9 * NN * NN;       // NB x 8 x NN x NN
    float* o_rt    = o_qh + (size_t)NB * NSTEPS * NN * NN;  // NB x NG x NG
    float* o_sp    = o_rt + (size_t)NB * NG * NG;           // scalar
    float* o_st    = o_sp + 1;                              // scalar

    float* nodes = (float*)d_ws;                            // NB*NN x ND
    float* proj  = nodes + (size_t)NB * NN * ND;            // NB*NN x ND
    float* sqv   = proj + (size_t)NB * NN * ND;             // NB*NN
    double* part = (double*)(((uintptr_t)(sqv + NB * NN) + 15) & ~(uintptr_t)15);  // 2*NB

    k_group_means<<<NB * NN, 256, 0, stream>>>(tokens, cls, nodes, ghp, gwp);
    dim3 g2((NB * NN) / 64, ND / 64);
    k_gemm_nt<<<g2, 256, 0, stream>>>(nodes, W, proj);
    k_normalize<<<NB * NN, 256, 0, stream>>>(proj, sqv);
    k_pairwise<<<NB, 256, 0, stream>>>(proj, sqv, o_dh);
    k_dynamics<<<NB, 64, 0, stream>>>(o_dh, o_qh, part);
    k_scores<<<NB, 256, 0, stream>>>(o_qh, local, ghp, gwp, o_keep, o_patch, o_gid, o_gs);
    k_routing<<<NB, 64, 0, stream>>>(o_dh, o_rt);
    k_aux<<<1, 64, 0, stream>>>(part, o_sp, o_st);
}

// Round 9
// 706.213 us; speedup vs baseline: 1.0040x; 1.0021x over previous
//
#include <hip/hip_runtime.h>
#include <stdint.h>

#define NB 64      // batch
#define NP 576     // patches
#define ND 768     // dim
#define NG 64      // groups
#define NN 65      // groups + 1 (cls)
#define NSTEPS 8
#define FLOORV 1.0e-4f
#define EPSV   1.0e-4f
#define DTV    0.1f
#define GAMMAV 0.1f
#define KEEPC  288  // max(1, round(576*0.5))

// ---------------------------------------------------------------- K1: group means
__global__ __launch_bounds__(256) void k_group_means(const float* __restrict__ tokens,
                                                     const float* __restrict__ cls,
                                                     float* __restrict__ nodes,
                                                     const int* __restrict__ ghp,
                                                     const int* __restrict__ gwp) {
    int bx = blockIdx.x;
    int b = bx / NN, n = bx - b * NN;
    int tid = threadIdx.x;
    float* orow = nodes + (size_t)bx * ND;
    if (n == 0) {
        for (int d = tid; d < ND; d += 256) orow[d] = cls[(size_t)b * ND + d];
        return;
    }
    int grid_h = *ghp, grid_w = *gwp;
    int gh = (grid_h + 7) / 8, gw = (grid_w + 7) / 8;
    int g = n - 1, gr = g >> 3, gc = g & 7;
    int r0 = gr * gh, r1 = (gr == 7) ? grid_h : min((gr + 1) * gh, grid_h);
    int c0 = gc * gw, c1 = (gc == 7) ? grid_w : min((gc + 1) * gw, grid_w);
    int cnt = (r1 > r0 && c1 > c0) ? (r1 - r0) * (c1 - c0) : 0;
    float cf = (float)max(cnt, 1);
    const float* tb = tokens + (size_t)b * NP * ND;
    for (int d = tid; d < ND; d += 256) {
        float acc = 0.f;
        for (int r = r0; r < r1; ++r)
            for (int c = c0; c < c1; ++c)
                acc += tb[(size_t)(r * grid_w + c) * ND + d];
        orow[d] = acc / cf;
    }
}

// ---------------------------------------------------------------- K2: proj = nodes @ W^T (NT gemm)
__global__ __launch_bounds__(256) void k_gemm_nt(const float* __restrict__ A,
                                                 const float* __restrict__ Bm,
                                                 float* __restrict__ Cm) {
    __shared__ float As[32][68];
    __shared__ float Bs[32][68];
    int tid = threadIdx.x;
    int m0 = blockIdx.x * 64, n0 = blockIdx.y * 64;
    int tx = tid & 15, ty = tid >> 4;
    float acc[4][4];
#pragma unroll
    for (int i = 0; i < 4; ++i)
#pragma unroll
        for (int j = 0; j < 4; ++j) acc[i][j] = 0.f;
    int lrow = tid >> 3, lq = tid & 7;
    for (int k0 = 0; k0 < ND; k0 += 32) {
#pragma unroll
        for (int l = 0; l < 2; ++l) {
            int row = lrow + l * 32;
            float4 va = *(const float4*)&A[(size_t)(m0 + row) * ND + k0 + lq * 4];
            As[lq * 4 + 0][row] = va.x; As[lq * 4 + 1][row] = va.y;
            As[lq * 4 + 2][row] = va.z; As[lq * 4 + 3][row] = va.w;
            float4 vb = *(const float4*)&Bm[(size_t)(n0 + row) * ND + k0 + lq * 4];
            Bs[lq * 4 + 0][row] = vb.x; Bs[lq * 4 + 1][row] = vb.y;
            Bs[lq * 4 + 2][row] = vb.z; Bs[lq * 4 + 3][row] = vb.w;
        }
        __syncthreads();
#pragma unroll
        for (int kk = 0; kk < 32; ++kk) {
            float4 a4 = *(const float4*)&As[kk][ty * 4];
            float4 b4 = *(const float4*)&Bs[kk][tx * 4];
            float av[4] = {a4.x, a4.y, a4.z, a4.w};
            float bv[4] = {b4.x, b4.y, b4.z, b4.w};
#pragma unroll
            for (int i = 0; i < 4; ++i)
#pragma unroll
                for (int j = 0; j < 4; ++j) acc[i][j] += av[i] * bv[j];
        }
        __syncthreads();
    }
#pragma unroll
    for (int i = 0; i < 4; ++i) {
        float4 o = make_float4(acc[i][0], acc[i][1], acc[i][2], acc[i][3]);
        *(float4*)&Cm[(size_t)(m0 + ty * 4 + i) * ND + n0 + tx * 4] = o;
    }
}

// ---------------------------------------------------------------- K3: row-normalize proj, sq = sum(projN^2)
__global__ __launch_bounds__(256) void k_normalize(float* __restrict__ proj, float* __restrict__ sqv) {
    int r = blockIdx.x, tid = threadIdx.x;
    __shared__ double red[8];
    __shared__ float invs;
    float* row = proj + (size_t)r * ND;
    double s = 0.0;
    for (int d = tid; d < ND; d += 256) { double v = (double)row[d]; s += v * v; }
#pragma unroll
    for (int off = 32; off; off >>= 1) s += __shfl_down(s, off, 64);
    int wid = tid >> 6, lane = tid & 63;
    if (lane == 0) red[wid] = s;
    __syncthreads();
    if (tid == 0) invs = (float)(1.0 / fmax(sqrt(red[0] + red[1] + red[2] + red[3]), 1e-12));
    __syncthreads();
    float inv = invs;
    double s2 = 0.0;
    for (int d = tid; d < ND; d += 256) {
        float v = row[d] * inv; row[d] = v; s2 += (double)v * (double)v;
    }
#pragma unroll
    for (int off = 32; off; off >>= 1) s2 += __shfl_down(s2, off, 64);
    __syncthreads();
    if (lane == 0) red[wid] = s2;
    __syncthreads();
    if (tid == 0) sqv[r] = (float)(red[0] + red[1] + red[2] + red[3]);
}

// ---------------------------------------------------------------- K4: C init = with_floor(exp(-d2)), write d_hist[:,0]
__global__ __launch_bounds__(256) void k_pairwise(const float* __restrict__ proj,
                                                  const float* __restrict__ sqv,
                                                  float* __restrict__ dhist) {
    int b = blockIdx.x, tid = threadIdx.x;
    int tx = tid & 15, ty = tid >> 4;
    __shared__ float Ps[NN][65];
    float acc[5][5];
#pragma unroll
    for (int a = 0; a < 5; ++a)
#pragma unroll
        for (int c = 0; c < 5; ++c) acc[a][c] = 0.f;
    const float* Pb = proj + (size_t)b * NN * ND;
    for (int k0 = 0; k0 < ND; k0 += 64) {
        __syncthreads();
        for (int idx = tid; idx < NN * 64; idx += 256) {
            int i = idx >> 6, kk = idx & 63;
            Ps[i][kk] = Pb[(size_t)i * ND + k0 + kk];
        }
        __syncthreads();
        for (int kk = 0; kk < 64; ++kk) {
            float av[5], bv[5];
#pragma unroll
            for (int a = 0; a < 5; ++a) { int i = ty + 16 * a; av[a] = (i < NN) ? Ps[i][kk] : 0.f; }
#pragma unroll
            for (int c = 0; c < 5; ++c) { int j = tx + 16 * c; bv[c] = (j < NN) ? Ps[j][kk] : 0.f; }
#pragma unroll
            for (int a = 0; a < 5; ++a)
#pragma unroll
                for (int c = 0; c < 5; ++c) acc[a][c] += av[a] * bv[c];
        }
    }
#pragma unroll
    for (int a = 0; a < 5; ++a)
#pragma unroll
        for (int c = 0; c < 5; ++c) {
            int i = ty + 16 * a, j = tx + 16 * c;
            if (i < NN && j < NN) {
                float d2 = fmaxf(sqv[b * NN + i] + sqv[b * NN + j] - 2.0f * acc[a][c], 0.f);
                double cv = exp(-(double)d2);   // TAU = 1
                float cf = (i == j) ? 0.f : fmaxf((float)cv, FLOORV);
                dhist[(size_t)b * 9 * NN * NN + (size_t)i * NN + j] = cf;
            }
        }
}

// ---------------------------------------------------------------- helper: readlane broadcast (literal lane)
__device__ __forceinline__ float rl(float v, int l) {
    return __int_as_float(__builtin_amdgcn_readlane(__float_as_int(v), l));
}

// ================================================================ K5 macro machinery
// BLOCKED register solve, designed UNDER the empirically-observed ~68-VGPR
// allocation cap (rounds 1-6: every full-row-in-registers variant allocated
// 52-72 VGPRs and spilled; r3==r6 perf proves SROA promoted and the ALLOCATOR
// spilled). Hold only 32 columns in registers at a time:
//   Phase A: rounds 0..32 on left cols 1..32 (regs a1..a32); multipliers l
//            stored to lds_L (left cols evolve independently of right cols ->
//            bit-identical to flat elimination order).
//   Dump a* -> lds_U (back-sub needs rows<=32's U), reload right cols 33..64
//            into b1..b32 (same physical regs, disjoint live ranges).
//   Phase B: replay rounds 0..32 on right cols (l from lds_L, pivot row via
//            readlane) -- per-element fma sequence identical to flat order.
//   Phase C: rounds 33..63 on right cols; then the r6 back-sub chain with
//            coefs from b* (I>=33) / lds_U (I<=32).
// Max live ~52 regs < 68 -> no spill by construction. One wave, no barriers.
// ROUND 9: kernel renamed k_dyn_blk for binary-identity attribution -- r8's
// "result" reported LDS_Block_Size=17408 (physically impossible here: this
// kernel declares ~34 KB) with counters byte-identical to r6 => stale binary.
// Kernel_Name in the counter CSV now proves which code executed.
#define REP32(M) \
  M(1) M(2) M(3) M(4) M(5) M(6) M(7) M(8) M(9) M(10) M(11) M(12) M(13) M(14) M(15) M(16) \
  M(17) M(18) M(19) M(20) M(21) M(22) M(23) M(24) M(25) M(26) M(27) M(28) M(29) M(30) M(31) M(32)

#define REP32_2(M, K) \
  M(1,K) M(2,K) M(3,K) M(4,K) M(5,K) M(6,K) M(7,K) M(8,K) M(9,K) M(10,K) M(11,K) M(12,K) \
  M(13,K) M(14,K) M(15,K) M(16,K) M(17,K) M(18,K) M(19,K) M(20,K) M(21,K) M(22,K) M(23,K) M(24,K) \
  M(25,K) M(26,K) M(27,K) M(28,K) M(29,K) M(30,K) M(31,K) M(32,K)

// build left: load, accumulate degree (order j=1..32), negate + diagonal fix
#define LDA(J)   float a##J = crow[J];
#define ACCA(J)  deg += a##J;
#define ACCR(J)  deg += crow[32 + (J)];
#define FIXA(J)  a##J = ((J) == i_own) ? diag : -a##J;
// round 0 on left cols (pivot row 0 read directly from Cs row 0 - broadcast)
#define R0A(J)   a##J = __builtin_fmaf(l0, Cs[(J)], a##J);
// phase A elimination round K (1..32): update left cols J>K
#define UPDA(J, K) if ((J) > (K)) a##J = __builtin_fmaf(ln, rl(a##J, (K) - 1), a##J);
#define ROUNDA(K) { \
    float pk = rl(a##K, (K) - 1); \
    float invp = 1.0f / pk; \
    inv_own = (lane == (K) - 1) ? invp : inv_own; \
    float l = (lane >= (K)) ? a##K * invp : 0.f; \
    lds_L[(K) * 64 + lane] = l; \
    float ln = -l; \
    REP32_2(UPDA, K) \
    ar = __builtin_fmaf(ln, rl(ar, (K) - 1), ar); \
  }
// dump left U, build right cols
#define DUMPA(J) lds_U[lane * 33 + (J)] = a##J;
#define LDB(J)   float b##J = ((32 + (J)) == i_own) ? diag : -crow[32 + (J)];
// phase B: replay round 0 then rounds 1..32 on right cols (all cols, no guard)
#define R0B(J)   b##J = __builtin_fmaf(l0, Cs[32 + (J)], b##J);
#define UPDB(J, K) b##J = __builtin_fmaf(ln, rl(b##J, (K) - 1), b##J);
#define ROUNDB(K) { \
    float l = lds_L[(K) * 64 + lane]; \
    float ln = -l; \
    REP32_2(UPDB, K) \
  }
// phase C round (Q = K-32, both literal): update right cols J with 32+J > K
#define UPDC(J, K) if (((J) + 32) > (K)) b##J = __builtin_fmaf(ln, rl(b##J, (K) - 1), b##J);
#define ROUNDC(Q, K) { \
    float pk = rl(b##Q, (K) - 1); \
    float invp = 1.0f / pk; \
    inv_own = (lane == (K) - 1) ? invp : inv_own; \
    float l = (lane >= (K)) ? b##Q * invp : 0.f; \
    float ln = -l; \
    REP32_2(UPDC, K) \
    ar = __builtin_fmaf(ln, rl(ar, (K) - 1), ar); \
  }
// back-substitution: high steps (I>=33, coef in regs), low steps (I<=32, coef in lds_U)
#define BSH(Q, I) { \
    float t = (rhs_ - acc) * inv_own; \
    float pi = rl(t, (I) - 1); \
    p_own = (i_own == (I)) ? t : p_own; \
    acc = __builtin_fmaf((i_own < (I)) ? b##Q : 0.f, pi, acc); \
  }
#define BSL(I) { \
    float t = (rhs_ - acc) * inv_own; \
    float pi = rl(t, (I) - 1); \
    p_own = (i_own == (I)) ? t : p_own; \
    float u = lds_U[lane * 33 + (I)]; \
    acc = __builtin_fmaf((i_own < (I)) ? u : 0.f, pi, acc); \
  }

// ---------------------------------------------------------------- K5: 8-step physarum dynamics
__global__ __launch_bounds__(64, 1) void k_dyn_blk(float* __restrict__ dhist,
                                                   float* __restrict__ qhist,
                                                   double* __restrict__ part) {
    int b = blockIdx.x;
    int lane = threadIdx.x;               // 0..63, one full wave
    __shared__ float Cs[NN * NN];         // conductance fp32 (16.9 KB)
    __shared__ float pd[NN];              // potentials
    __shared__ float lds_L[33 * 64];      // phase-A multipliers (8.4 KB)
    __shared__ float lds_U[64 * 33];      // dumped left-U rows (8.4 KB)
    float* C0 = dhist + (size_t)b * 9 * NN * NN;
    for (int t = lane; t < NN * NN; t += 64) Cs[t] = C0[t];
    __threadfence_block();

    const int i_own = lane + 1;           // row owned by this lane (1..64)
    double stable = 0.0, sparse = 0.0;

#pragma unroll 1
    for (int step = 0; step < NSTEPS; ++step) {
        const float* crow = Cs + (size_t)i_own * NN;
        // ---- build: deg summed in flat order j=0..64 (bit-identical to r1-r6)
        float c0v = crow[0];
        float deg = c0v;
        REP32(LDA)                         // a1..a32 = crow[1..32]
        REP32(ACCA)                        // deg += a1..a32 (order 1..32)
        REP32(ACCR)                        // deg += crow[33..64] (order 33..64)
        float diag = deg + EPSV;
        REP32(FIXA)                        // negate off-diag, install diagonal (left)
        float ar = -(1.0f / 64.0f);        // rhs for rows >= 1

        // ---- round 0 on left cols (pivot = system row 0)
        float v0 = Cs[lane + 1];           // C[0][lane+1]
        float s0 = v0;
#pragma unroll
        for (int off = 1; off < 64; off <<= 1) s0 += __shfl_xor(s0, off, 64);
        float d0 = s0 + EPSV;              // A[0][0]
        float invd0 = 1.0f / d0;
        float l0 = -c0v * invd0;           // A[i][0] / A[0][0]
        REP32(R0A)                         // a_J += l0 * C[0][J]
        ar -= l0;                          // rhs -= l0 * 1

        // ---- phase A: rounds 1..32 on left cols, l recorded to lds_L
        float inv_own = 0.f;
        ROUNDA(1)  ROUNDA(2)  ROUNDA(3)  ROUNDA(4)  ROUNDA(5)  ROUNDA(6)  ROUNDA(7)  ROUNDA(8)
        ROUNDA(9)  ROUNDA(10) ROUNDA(11) ROUNDA(12) ROUNDA(13) ROUNDA(14) ROUNDA(15) ROUNDA(16)
        ROUNDA(17) ROUNDA(18) ROUNDA(19) ROUNDA(20) ROUNDA(21) ROUNDA(22) ROUNDA(23) ROUNDA(24)
        ROUNDA(25) ROUNDA(26) ROUNDA(27) ROUNDA(28) ROUNDA(29) ROUNDA(30) ROUNDA(31) ROUNDA(32)

        // ---- dump left U, load right cols (a* die here; b* reuse the regs)
        REP32(DUMPA)
        REP32(LDB)                         // b1..b32 = original right cols (+diag)

        // ---- phase B: replay rounds 0..32 on right cols (bit-identical order)
        REP32(R0B)                         // round 0: pivot row 0 right half from Cs
        ROUNDB(1)  ROUNDB(2)  ROUNDB(3)  ROUNDB(4)  ROUNDB(5)  ROUNDB(6)  ROUNDB(7)  ROUNDB(8)
        ROUNDB(9)  ROUNDB(10) ROUNDB(11) ROUNDB(12) ROUNDB(13) ROUNDB(14) ROUNDB(15) ROUNDB(16)
        ROUNDB(17) ROUNDB(18) ROUNDB(19) ROUNDB(20) ROUNDB(21) ROUNDB(22) ROUNDB(23) ROUNDB(24)
        ROUNDB(25) ROUNDB(26) ROUNDB(27) ROUNDB(28) ROUNDB(29) ROUNDB(30) ROUNDB(31) ROUNDB(32)

        // ---- phase C: rounds 33..63 on right cols
        ROUNDC(1,33)  ROUNDC(2,34)  ROUNDC(3,35)  ROUNDC(4,36)  ROUNDC(5,37)  ROUNDC(6,38)
        ROUNDC(7,39)  ROUNDC(8,40)  ROUNDC(9,41)  ROUNDC(10,42) ROUNDC(11,43) ROUNDC(12,44)
        ROUNDC(13,45) ROUNDC(14,46) ROUNDC(15,47) ROUNDC(16,48) ROUNDC(17,49) ROUNDC(18,50)
        ROUNDC(19,51) ROUNDC(20,52) ROUNDC(21,53) ROUNDC(22,54) ROUNDC(23,55) ROUNDC(24,56)
        ROUNDC(25,57) ROUNDC(26,58) ROUNDC(27,59) ROUNDC(28,60) ROUNDC(29,61) ROUNDC(30,62)
        ROUNDC(31,63)
        {   // round 64: capture last diagonal reciprocal
            float pk = rl(b32, 63);
            float invp = 1.0f / pk;
            inv_own = (lane == 63) ? invp : inv_own;
        }

        // ---- back substitution (descending I=64..1, same chain as r6)
        float rhs_ = ar;
        float acc = 0.f, p_own = 0.f;
        BSH(32,64) BSH(31,63) BSH(30,62) BSH(29,61) BSH(28,60) BSH(27,59) BSH(26,58) BSH(25,57)
        BSH(24,56) BSH(23,55) BSH(22,54) BSH(21,53) BSH(20,52) BSH(19,51) BSH(18,50) BSH(17,49)
        BSH(16,48) BSH(15,47) BSH(14,46) BSH(13,45) BSH(12,44) BSH(11,43) BSH(10,42) BSH(9,41)
        BSH(8,40)  BSH(7,39)  BSH(6,38)  BSH(5,37)  BSH(4,36)  BSH(3,35)  BSH(2,34)  BSH(1,33)
        BSL(32) BSL(31) BSL(30) BSL(29) BSL(28) BSL(27) BSL(26) BSL(25)
        BSL(24) BSL(23) BSL(22) BSL(21) BSL(20) BSL(19) BSL(18) BSL(17)
        BSL(16) BSL(15) BSL(14) BSL(13) BSL(12) BSL(11) BSL(10) BSL(9)
        BSL(8)  BSL(7)  BSL(6)  BSL(5)  BSL(4)  BSL(3)  BSL(2)  BSL(1)
        pd[i_own] = p_own;
        // p0 = (1 + sum_j C[0][j]*p_j) / d0  (row 0 never modified)
        float sp = v0 * p_own;
#pragma unroll
        for (int off = 1; off < 64; off <<= 1) sp += __shfl_xor(sp, off, 64);
        if (lane == 0) pd[0] = (1.0f + sp) * invd0;
        __threadfence_block();

        // ---- flow + conductance update (fp32, matches reference)
        float* qout = qhist + ((size_t)b * NSTEPS + step) * NN * NN;
        float* dout = dhist + ((size_t)b * 9 + step + 1) * NN * NN;
        for (int t = lane; t < NN * NN; t += 64) {
            int i = t / NN, j = t - i * NN;
            float c = Cs[t];
            float fl = c * (pd[i] - pd[j]);
            qout[t] = fl;
            float rr = fabsf(fl); rr = rr / (1.0f + rr);
            float cn = c + DTV * (rr - GAMMAV * c);
            float cnf = (i == j) ? 0.0f : fmaxf(cn, FLOORV);
            Cs[t] = cnf;
            dout[t] = cnf;
            stable += fabs((double)cnf - (double)c);
            if (step == NSTEPS - 1 && i > 0 && j > 0) sparse += (double)cnf;
        }
        __threadfence_block();
    }

#pragma unroll
    for (int off = 32; off; off >>= 1) {
        stable += __shfl_down(stable, off, 64);
        sparse += __shfl_down(sparse, off, 64);
    }
    if (lane == 0) {
        part[b]      = sparse;
        part[NB + b] = stable;
    }
}

// ---------------------------------------------------------------- K6: scores, top-k masks, gid, group_scores
__global__ __launch_bounds__(256) void k_scores(const float* __restrict__ qhist,
                                                const float* __restrict__ local,
                                                const int* __restrict__ ghp,
                                                const int* __restrict__ gwp,
                                                float* __restrict__ keep,
                                                float* __restrict__ patch,
                                                float* __restrict__ gidout,
                                                float* __restrict__ gsout) {
    int b = blockIdx.x, tid = threadIdx.x;
    __shared__ double gf[NG];
    __shared__ double ts[NP];
    __shared__ double red[8];
    __shared__ double stats[2];
    if (tid < NG) {
        const float* qrow = qhist + ((size_t)b * NSTEPS + (NSTEPS - 1)) * NN * NN + (size_t)(tid + 1) * NN;
        double s = 0.0;
        for (int j = 0; j < NN; ++j) s += fabs((double)qrow[j]);
        gf[tid] = s;
    }
    __syncthreads();
    if (tid < 64) {
        double v = gf[tid];
        double s = v;
#pragma unroll
        for (int off = 32; off; off >>= 1) s += __shfl_down(s, off, 64);
        double mean = __shfl(s, 0, 64) / (double)NG;
        double d = v - mean, ss = d * d;
#pragma unroll
        for (int off = 32; off; off >>= 1) ss += __shfl_down(ss, off, 64);
        if (tid == 0) { stats[0] = mean; stats[1] = 1.0 / fmax(sqrt(ss / (NG - 1)), 1e-6); }
    }
    const float* lrow = local + (size_t)b * NP;
    double s1 = 0.0;
    for (int p = tid; p < NP; p += 256) s1 += (double)lrow[p];
#pragma unroll
    for (int off = 32; off; off >>= 1) s1 += __shfl_down(s1, off, 64);
    int wid = tid >> 6, lane = tid & 63;
    if (lane == 0) red[wid] = s1;
    __syncthreads();
    double lmean = (red[0] + red[1] + red[2] + red[3]) / (double)NP;
    double s2 = 0.0;
    for (int p = tid; p < NP; p += 256) { double d = (double)lrow[p] - lmean; s2 += d * d; }
#pragma unroll
    for (int off = 32; off; off >>= 1) s2 += __shfl_down(s2, off, 64);
    __syncthreads();
    if (lane == 0) red[wid] = s2;
    __syncthreads();
    double linv = 1.0 / fmax(sqrt((red[0] + red[1] + red[2] + red[3]) / (double)(NP - 1)), 1e-6);
    double gmean = stats[0], ginv = stats[1];
    int grid_h = *ghp, grid_w = *gwp;
    int gh = (grid_h + 7) / 8, gw = (grid_w + 7) / 8;
    for (int p = tid; p < NP; p += 256) {
        int row = p / grid_w, col = p - row * grid_w;
        int g = min(row / gh, 7) * 8 + min(col / gw, 7);
        double gsc = (gf[g] - gmean) * ginv;
        double lsc = ((double)lrow[p] - lmean) * linv;
        ts[p] = gsc + 0.5 * lsc;  // FLOW_W=1, LOCAL_W=0.5
        gidout[(size_t)b * NP + p] = (float)g;
        gsout[(size_t)b * NP + p]  = (float)gsc;
    }
    __syncthreads();
    for (int p = tid; p < NP; p += 256) {
        double sp = ts[p];
        int c = 0;
        for (int qq = 0; qq < NP; ++qq) {
            double v = ts[qq];
            c += (v > sp) || (v == sp && qq < p);
        }
        float kf = (c < KEEPC) ? 1.0f : 0.0f;
        patch[(size_t)b * NP + p] = kf;
        keep[(size_t)b * (NP + 1) + 1 + p] = kf;
    }
    if (tid == 0) keep[(size_t)b * (NP + 1)] = 1.0f;
}

// ---------------------------------------------------------------- K7: routing rows
__global__ void k_routing(const float* __restrict__ dhist, float* __restrict__ rout) {
    int b = blockIdx.x, tid = threadIdx.x;  // 64 threads
    const float* Crow = dhist + ((size_t)b * 9 + 8) * NN * NN + (size_t)(tid + 1) * NN + 1;
    double s = 0.0;
    for (int j = 0; j < NG; ++j) s += (double)Crow[j];
    double inv = 1.0 / fmax(s, 1e-6);
    float* orow = rout + ((size_t)b * NG + tid) * NG;
    for (int j = 0; j < NG; ++j) orow[j] = (float)((double)Crow[j] * inv);
}

// ---------------------------------------------------------------- K8: aux scalar reduction
__global__ void k_aux(const double* __restrict__ part, float* __restrict__ osp, float* __restrict__ ost) {
    int tid = threadIdx.x;  // 64 threads
    double sp = part[tid], st = part[NB + tid];
#pragma unroll
    for (int off = 32; off; off >>= 1) {
        sp += __shfl_down(sp, off, 64);
        st += __shfl_down(st, off, 64);
    }
    if (tid == 0) { *osp = (float)(sp / NB); *ost = (float)(st / NB); }
}

// ----------------------------------------------------------------
extern "C" void kernel_launch(void* const* d_in, const int* in_sizes, int n_in,
                              void* d_out, int out_size, void* d_ws, size_t ws_size,
                              hipStream_t stream) {
    const float* tokens = (const float*)d_in[0];
    const float* cls    = (const float*)d_in[1];
    const float* W      = (const float*)d_in[2];
    const float* local  = (const float*)d_in[3];
    const int* ghp = (const int*)d_in[4];
    const int* gwp = (const int*)d_in[5];

    float* out = (float*)d_out;
    float* o_keep  = out;                                   // NB x (NP+1)
    float* o_patch = o_keep + (size_t)NB * (NP + 1);        // NB x NP
    float* o_gid   = o_patch + (size_t)NB * NP;             // NB x NP
    float* o_gs    = o_gid + (size_t)NB * NP;               // NB x NP
    float* o_dh    = o_gs + (size_t)NB * NP;                // NB x 9 x NN x NN
    float* o_qh    = o_dh + (size_t)NB * 9 * NN * NN;       // NB x 8 x NN x NN
    float* o_rt    = o_qh + (size_t)NB * NSTEPS * NN * NN;  // NB x NG x NG
    float* o_sp    = o_rt + (size_t)NB * NG * NG;           // scalar
    float* o_st    = o_sp + 1;                              // scalar

    float* nodes = (float*)d_ws;                            // NB*NN x ND
    float* proj  = nodes + (size_t)NB * NN * ND;            // NB*NN x ND
    float* sqv   = proj + (size_t)NB * NN * ND;             // NB*NN
    double* part = (double*)(((uintptr_t)(sqv + NB * NN) + 15) & ~(uintptr_t)15);  // 2*NB

    k_group_means<<<NB * NN, 256, 0, stream>>>(tokens, cls, nodes, ghp, gwp);
    dim3 g2((NB * NN) / 64, ND / 64);
    k_gemm_nt<<<g2, 256, 0, stream>>>(nodes, W, proj);
    k_normalize<<<NB * NN, 256, 0, stream>>>(proj, sqv);
    k_pairwise<<<NB, 256, 0, stream>>>(proj, sqv, o_dh);
    k_dyn_blk<<<NB, 64, 0, stream>>>(o_dh, o_qh, part);
    k_scores<<<NB, 256, 0, stream>>>(o_qh, local, ghp, gwp, o_keep, o_patch, o_gid, o_gs);
    k_routing<<<NB, 64, 0, stream>>>(o_dh, o_rt);
    k_aux<<<1, 64, 0, stream>>>(part, o_sp, o_st);
}